// Round 2
// baseline (138.035 us; speedup 1.0000x reference)
//
#include <hip/hip_runtime.h>
#include <hip/hip_bf16.h>

// Problem constants (B=2, T=1024, C=256, H=128, HD=2). All I/O is float32.
#define T_SEQ   1024
#define C_DIM   256
#define H_HEADS 128
#define NTOK    2048   // B*T
#define BH      256    // B*H

#define LDA 68         // 64 + 4 pad: 272B row stride, 16B-aligned

// ---------------------------------------------------------------------------
// Kernel 1: qkv = x @ w_qkv^T  (M=2048, N=768, K=256) fp32, fused RMSNorm
// (HD=2) on q,k sections.  Writes q fp32 [BH][T][2] and kv fp32 [BH][T][4]
// (kx,ky,vx,vy packed for single-b128 attention reads).
// Tile 64x64, K staged in 4 chunks of 64; 256 threads, 4x4 micro-tile.
// B staged transposed in LDS -> conflict-free b128 compute reads.
// ---------------------------------------------------------------------------
__global__ __launch_bounds__(256) void k_qkv(
    const float* __restrict__ x, const float* __restrict__ wqkv,
    const float* __restrict__ qnw, const float* __restrict__ knw,
    float* __restrict__ q, float* __restrict__ kv)
{
  __shared__ float sA[64][LDA];    // x tile, row-major [m][k]
  __shared__ float sBT[64][LDA];   // w tile, transposed [k][n]

  const int tid  = threadIdx.x;
  const int row0 = blockIdx.x * 64;   // 32 blocks
  const int col0 = blockIdx.y * 64;   // 12 blocks

  const int r4 = (tid >> 4) * 4;   // rows r4..r4+3
  const int c4 = (tid & 15) * 4;   // cols c4..c4+3

  float acc[4][4] = {};

  for (int kc = 0; kc < 4; ++kc) {
    const int k0 = kc * 64;
    // stage A: 64x64 floats = 1024 float4, 4 per thread
#pragma unroll
    for (int it = 0; it < 4; ++it) {
      int idx = it * 256 + tid;
      int r = idx >> 4, m = (idx & 15) * 4;
      *(float4*)&sA[r][m] = *(const float4*)&x[(row0 + r) * C_DIM + k0 + m];
    }
    // stage B transposed: load w[col0+n][k0+m*4..], scatter to sBT[k][n]
#pragma unroll
    for (int it = 0; it < 4; ++it) {
      int idx = it * 256 + tid;
      int n = idx >> 4, m = (idx & 15) * 4;
      float4 wv = *(const float4*)&wqkv[(col0 + n) * C_DIM + k0 + m];
      sBT[m + 0][n] = wv.x;
      sBT[m + 1][n] = wv.y;
      sBT[m + 2][n] = wv.z;
      sBT[m + 3][n] = wv.w;
    }
    __syncthreads();

    for (int kk = 0; kk < 64; kk += 4) {
      float b[4][4];
      *(float4*)&b[0][0] = *(const float4*)&sBT[kk + 0][c4];
      *(float4*)&b[1][0] = *(const float4*)&sBT[kk + 1][c4];
      *(float4*)&b[2][0] = *(const float4*)&sBT[kk + 2][c4];
      *(float4*)&b[3][0] = *(const float4*)&sBT[kk + 3][c4];
#pragma unroll
      for (int r = 0; r < 4; ++r) {
        float a[4];
        *(float4*)&a[0] = *(const float4*)&sA[r4 + r][kk];
#pragma unroll
        for (int p = 0; p < 4; ++p)
#pragma unroll
          for (int j = 0; j < 4; ++j)
            acc[r][j] = fmaf(a[p], b[p][j], acc[r][j]);
      }
    }
    __syncthreads();
  }

  // epilogue: section uniform per block (col0 multiple of 64)
  const int sec = col0 >> 8;                  // 0=q, 1=k, 2=v
  const int h0  = ((col0 & 255) + c4) >> 1;   // first of 2 heads this thread
  float w0 = 1.f, w1 = 1.f;
  if (sec == 0) { w0 = qnw[0]; w1 = qnw[1]; }
  if (sec == 1) { w0 = knw[0]; w1 = knw[1]; }

#pragma unroll
  for (int r = 0; r < 4; ++r) {
    int n = row0 + r4 + r;
    int b = n >> 10, t = n & 1023;
#pragma unroll
    for (int p = 0; p < 2; ++p) {
      float a0 = acc[r][2 * p], a1 = acc[r][2 * p + 1];
      if (sec < 2) {
        float rr = rsqrtf(0.5f * (a0 * a0 + a1 * a1) + 1e-6f);
        a0 = a0 * rr * w0;
        a1 = a1 * rr * w1;
      }
      int bh = b * H_HEADS + (h0 + p);
      float2 o = make_float2(a0, a1);
      if (sec == 0)      *(float2*)&q [(bh * T_SEQ + t) * 2]     = o;
      else if (sec == 1) *(float2*)&kv[(bh * T_SEQ + t) * 4]     = o;
      else               *(float2*)&kv[(bh * T_SEQ + t) * 4 + 2] = o;
    }
  }
}

// ---------------------------------------------------------------------------
// Kernel 2: attention. Block = (head, group of 256 queries). RMSNormed q,k
// with w=1 bound |score| <= ~1.45, so single-pass softmax without running
// max is numerically safe. 256 threads = 4 waves; each LANE owns 4 queries
// (qb + j*64 + lane) so the broadcast float4 kv read amortizes 4x; each WAVE
// covers 1/4 of the key range; partials reduced through LDS.
// ---------------------------------------------------------------------------
__global__ __launch_bounds__(256) void k_attn(
    const float* __restrict__ q, const float* __restrict__ kv,
    float* __restrict__ y)
{
  __shared__ float4 skv[T_SEQ];         // 16 KB
  __shared__ float  red[4][256][3];     // 12 KB

  const int tid  = threadIdx.x;
  const int head = blockIdx.x;          // 0..255 (= b*128 + h)
  const int g    = 3 - blockIdx.y;      // heavy groups dispatched first
  const int qb   = g * 256;
  const int S    = qb + 256;            // keys needed (causal)
  const int lane = tid & 63;
  const int w    = tid >> 6;

  const float4* kvh = (const float4*)(kv + head * (T_SEQ * 4));
  for (int i = tid; i < S; i += 256) skv[i] = kvh[i];

  const float scale = 0.70710678118f;   // 1/sqrt(HD=2)
  float qxs[4], qys[4];
  int   tq[4];
#pragma unroll
  for (int j = 0; j < 4; ++j) {
    tq[j] = qb + j * 64 + lane;
    float2 qv = *(const float2*)&q[(head * T_SEQ + tq[j]) * 2];
    qxs[j] = qv.x * scale;
    qys[j] = qv.y * scale;
  }
  __syncthreads();

  float den[4] = {}, nx[4] = {}, ny[4] = {};
  const int chunk = S >> 2;             // 64..256, multiple of 64
  const int s0 = w * chunk, s1 = s0 + chunk;
  for (int s = s0; s < s1; ++s) {
    float4 kvv = skv[s];
#pragma unroll
    for (int j = 0; j < 4; ++j) {
      float sc = fmaf(qxs[j], kvv.x, qys[j] * kvv.y);
      float e  = __expf(sc);
      e = (s <= tq[j]) ? e : 0.f;
      den[j] += e;
      nx[j] = fmaf(e, kvv.z, nx[j]);
      ny[j] = fmaf(e, kvv.w, ny[j]);
    }
  }
#pragma unroll
  for (int j = 0; j < 4; ++j) {
    red[w][j * 64 + lane][0] = den[j];
    red[w][j * 64 + lane][1] = nx[j];
    red[w][j * 64 + lane][2] = ny[j];
  }
  __syncthreads();

  // thread tid finalizes query qb+tid
  float d = 0.f, ax = 0.f, ay = 0.f;
#pragma unroll
  for (int ww = 0; ww < 4; ++ww) {
    d  += red[ww][tid][0];
    ax += red[ww][tid][1];
    ay += red[ww][tid][2];
  }
  float inv = 1.f / d;
  int b = head >> 7, h = head & 127;
  int t = qb + tid;
  // y layout [B*T][C], col = 2h+d — ready for the proj GEMM
  *(float2*)&y[(b * T_SEQ + t) * C_DIM + h * 2] = make_float2(ax * inv, ay * inv);
}

// ---------------------------------------------------------------------------
// Kernel 3: out = y @ w_proj^T (M=2048, N=256, K=256) fp32. Same GEMM
// structure as k_qkv, plain fp32 output.
// ---------------------------------------------------------------------------
__global__ __launch_bounds__(256) void k_proj(
    const float* __restrict__ y, const float* __restrict__ wproj,
    float* __restrict__ out)
{
  __shared__ float sA[64][LDA];
  __shared__ float sBT[64][LDA];

  const int tid  = threadIdx.x;
  const int row0 = blockIdx.x * 64;   // 32 blocks
  const int col0 = blockIdx.y * 64;   // 4 blocks

  const int r4 = (tid >> 4) * 4;
  const int c4 = (tid & 15) * 4;

  float acc[4][4] = {};

  for (int kc = 0; kc < 4; ++kc) {
    const int k0 = kc * 64;
#pragma unroll
    for (int it = 0; it < 4; ++it) {
      int idx = it * 256 + tid;
      int r = idx >> 4, m = (idx & 15) * 4;
      *(float4*)&sA[r][m] = *(const float4*)&y[(row0 + r) * C_DIM + k0 + m];
    }
#pragma unroll
    for (int it = 0; it < 4; ++it) {
      int idx = it * 256 + tid;
      int n = idx >> 4, m = (idx & 15) * 4;
      float4 wv = *(const float4*)&wproj[(col0 + n) * C_DIM + k0 + m];
      sBT[m + 0][n] = wv.x;
      sBT[m + 1][n] = wv.y;
      sBT[m + 2][n] = wv.z;
      sBT[m + 3][n] = wv.w;
    }
    __syncthreads();

    for (int kk = 0; kk < 64; kk += 4) {
      float b[4][4];
      *(float4*)&b[0][0] = *(const float4*)&sBT[kk + 0][c4];
      *(float4*)&b[1][0] = *(const float4*)&sBT[kk + 1][c4];
      *(float4*)&b[2][0] = *(const float4*)&sBT[kk + 2][c4];
      *(float4*)&b[3][0] = *(const float4*)&sBT[kk + 3][c4];
#pragma unroll
      for (int r = 0; r < 4; ++r) {
        float a[4];
        *(float4*)&a[0] = *(const float4*)&sA[r4 + r][kk];
#pragma unroll
        for (int p = 0; p < 4; ++p)
#pragma unroll
          for (int j = 0; j < 4; ++j)
            acc[r][j] = fmaf(a[p], b[p][j], acc[r][j]);
      }
    }
    __syncthreads();
  }

#pragma unroll
  for (int r = 0; r < 4; ++r)
    *(float4*)&out[(row0 + r4 + r) * C_DIM + col0 + c4] = *(float4*)&acc[r][0];
}

// ---------------------------------------------------------------------------
extern "C" void kernel_launch(void* const* d_in, const int* in_sizes, int n_in,
                              void* d_out, int out_size, void* d_ws, size_t ws_size,
                              hipStream_t stream) {
  const float* x     = (const float*)d_in[0];
  const float* wqkv  = (const float*)d_in[1];
  const float* wproj = (const float*)d_in[2];
  const float* qnw   = (const float*)d_in[3];
  const float* knw   = (const float*)d_in[4];

  float* ws = (float*)d_ws;
  float* q  = ws;                       // [BH][T][2]  = 524288 floats (2 MB)
  float* kv = q  + BH * T_SEQ * 2;      // [BH][T][4]  = 1048576 floats (4 MB)
  float* yb = kv + BH * T_SEQ * 4;      // [NTOK][C]   = 524288 floats (2 MB)

  k_qkv <<<dim3(NTOK / 64, 768 / 64), 256, 0, stream>>>(x, wqkv, qnw, knw, q, kv);
  k_attn<<<dim3(BH, 4),               256, 0, stream>>>(q, kv, yb);
  k_proj<<<dim3(NTOK / 64, C_DIM / 64), 256, 0, stream>>>(yb, wproj, (float*)d_out);
}

// Round 3
// 135.718 us; speedup vs baseline: 1.0171x; 1.0171x over previous
//
#include <hip/hip_runtime.h>
#include <hip/hip_bf16.h>

// Problem constants (B=2, T=1024, C=256, H=128, HD=2). All I/O is float32.
#define T_SEQ   1024
#define C_DIM   256
#define H_HEADS 128
#define NTOK    2048   // B*T
#define BH      256    // B*H

typedef unsigned short u16;
typedef unsigned int   u32;
typedef __attribute__((ext_vector_type(8))) short bf16x8;  // MFMA A/B frag
typedef __attribute__((ext_vector_type(4))) float f32x4;   // MFMA C/D frag

__device__ __forceinline__ float bf2f(u16 u) {
  return __uint_as_float(((u32)u) << 16);
}
__device__ __forceinline__ u16 f2bf(float f) {  // RNE (no NaN in this problem)
  u32 u = __float_as_uint(f);
  u32 r = u + 0x7fffu + ((u >> 16) & 1u);
  return (u16)(r >> 16);
}

// ---------------------------------------------------------------------------
// MFMA GEMM core: out = X @ W^T, X:[M][256] fp32, W:[N][256] fp32.
// fp32 -> bf16 hi/lo split (x = hi + lo); D = Ahi*Bhi + Ahi*Blo + Alo*Bhi.
// Block tile 64x64, K chunked by 64; 256 threads = 4 waves.
// Wave w: col-tile w (cols w*16..w*16+15), row-tiles 0..3.
// Fragment layout (verified m89/m91/m92): A[m=lane&15][k=(lane>>4)*8+j],
// B from row-major [n][k] with the same pattern; C/D row=(lane>>4)*4+i,
// col=lane&15.
// LDS pad: 72 u16 per row = 144 B stride (16B-aligned, uniform bank spread).
// ---------------------------------------------------------------------------
#define LDS_K 72

// stage a 64x64 fp32 tile as hi/lo bf16 into LDS; 4 float4 per thread
__device__ __forceinline__ void stage_hilo(
    const float* __restrict__ src, int row0, int k0, int tid,
    u16 (*hi)[LDS_K], u16 (*lo)[LDS_K])
{
#pragma unroll
  for (int it = 0; it < 4; ++it) {
    int idx = it * 256 + tid;
    int r = idx >> 4, c4 = (idx & 15) * 4;
    float4 g = *(const float4*)&src[(row0 + r) * C_DIM + k0 + c4];
    ushort4 h4, l4;
    h4.x = f2bf(g.x); l4.x = f2bf(g.x - bf2f(h4.x));
    h4.y = f2bf(g.y); l4.y = f2bf(g.y - bf2f(h4.y));
    h4.z = f2bf(g.z); l4.z = f2bf(g.z - bf2f(h4.z));
    h4.w = f2bf(g.w); l4.w = f2bf(g.w - bf2f(h4.w));
    *(ushort4*)&hi[r][c4] = h4;
    *(ushort4*)&lo[r][c4] = l4;
  }
}

// compute one 64-wide K chunk: 4 row-tiles x 1 col-tile per wave
__device__ __forceinline__ void mfma_chunk(
    const u16 (*sXhi)[LDS_K], const u16 (*sXlo)[LDS_K],
    const u16 (*sWhi)[LDS_K], const u16 (*sWlo)[LDS_K],
    int lane, int w, f32x4* acc)
{
  const int fr = lane & 15;          // fragment row within tile
  const int ko = (lane >> 4) * 8;    // fragment k offset
#pragma unroll
  for (int ks = 0; ks < 2; ++ks) {
    const int kk = ks * 32 + ko;
    bf16x8 bhi = *(const bf16x8*)&sWhi[w * 16 + fr][kk];
    bf16x8 blo = *(const bf16x8*)&sWlo[w * 16 + fr][kk];
#pragma unroll
    for (int rt = 0; rt < 4; ++rt) {
      bf16x8 ahi = *(const bf16x8*)&sXhi[rt * 16 + fr][kk];
      bf16x8 alo = *(const bf16x8*)&sXlo[rt * 16 + fr][kk];
      acc[rt] = __builtin_amdgcn_mfma_f32_16x16x32_bf16(alo, bhi, acc[rt], 0, 0, 0);
      acc[rt] = __builtin_amdgcn_mfma_f32_16x16x32_bf16(ahi, blo, acc[rt], 0, 0, 0);
      acc[rt] = __builtin_amdgcn_mfma_f32_16x16x32_bf16(ahi, bhi, acc[rt], 0, 0, 0);
    }
  }
}

// ---------------------------------------------------------------------------
// Kernel 1: qkv = x @ w_qkv^T (M=2048, N=768, K=256), fused RMSNorm (HD=2)
// on q,k sections; q fp32 [BH][T][2], kv fp32 [BH][T][4] (kx,ky,vx,vy).
// ---------------------------------------------------------------------------
__global__ __launch_bounds__(256) void k_qkv(
    const float* __restrict__ x, const float* __restrict__ wqkv,
    const float* __restrict__ qnw, const float* __restrict__ knw,
    float* __restrict__ q, float* __restrict__ kv)
{
  __shared__ u16 sXhi[64][LDS_K], sXlo[64][LDS_K];
  __shared__ u16 sWhi[64][LDS_K], sWlo[64][LDS_K];

  const int tid  = threadIdx.x;
  const int lane = tid & 63;
  const int w    = tid >> 6;
  const int row0 = blockIdx.x * 64;   // 32
  const int col0 = blockIdx.y * 64;   // 12

  f32x4 acc[4] = {};

  for (int kc = 0; kc < 4; ++kc) {
    stage_hilo(x,    row0, kc * 64, tid, sXhi, sXlo);
    stage_hilo(wqkv, col0, kc * 64, tid, sWhi, sWlo);
    __syncthreads();
    mfma_chunk(sXhi, sXlo, sWhi, sWlo, lane, w, acc);
    __syncthreads();
  }

  // epilogue: section uniform per block (col0 multiple of 64, sections 256)
  const int sec = col0 >> 8;                       // 0=q, 1=k, 2=v
  const int cg  = col0 + w * 16 + (lane & 15);     // global col
  const int d   = cg & 1;
  const int h   = (cg & 255) >> 1;
  const float wn = (sec == 0) ? qnw[d] : (sec == 1) ? knw[d] : 1.f;

#pragma unroll
  for (int rt = 0; rt < 4; ++rt) {
#pragma unroll
    for (int i = 0; i < 4; ++i) {
      float val = acc[rt][i];
      int n = row0 + rt * 16 + (lane >> 4) * 4 + i;   // token
      int b = n >> 10, t = n & 1023;
      int bh = b * H_HEADS + h;
      if (sec < 2) {
        float pv = __shfl_xor(val, 1);                // partner col of the pair
        float rr = rsqrtf(0.5f * (val * val + pv * pv) + 1e-6f);
        val = val * rr * wn;
      }
      if (sec == 0)      q [(bh * T_SEQ + t) * 2 + d]     = val;
      else if (sec == 1) kv[(bh * T_SEQ + t) * 4 + d]     = val;
      else               kv[(bh * T_SEQ + t) * 4 + 2 + d] = val;
    }
  }
}

// ---------------------------------------------------------------------------
// Kernel 2: attention. Block = (head, group of 256 queries). RMSNormed q,k
// bound |score*scale| <= sqrt2 -> single-pass softmax, no running max.
// 4 waves split keys; each lane owns 4 queries (qb+j*64+lane). Bulk region
// [0,qb) needs no causal mask; diagonal region [qb,qb+256) keeps the mask.
// scale*log2e folded into q so exp2 (v_exp_f32) is used directly.
// ---------------------------------------------------------------------------
__global__ __launch_bounds__(256) void k_attn(
    const float* __restrict__ q, const float* __restrict__ kv,
    float* __restrict__ y)
{
  __shared__ float4 skv[T_SEQ];         // 16 KB
  __shared__ float  red[4][256][3];     // 12 KB

  const int tid  = threadIdx.x;
  const int head = blockIdx.x;          // 0..255
  const int g    = 3 - blockIdx.y;      // heavy groups dispatched first
  const int qb   = g * 256;
  const int S    = qb + 256;
  const int lane = tid & 63;
  const int w    = tid >> 6;

  const float4* kvh = (const float4*)(kv + head * (T_SEQ * 4));
  for (int i = tid; i < S; i += 256) skv[i] = kvh[i];

  const float LS = 0.70710678118f * 1.44269504089f;  // scale * log2(e)
  float qx[4], qy[4];
  int   tq[4];
#pragma unroll
  for (int j = 0; j < 4; ++j) {
    tq[j] = qb + j * 64 + lane;
    float2 qv = *(const float2*)&q[(head * T_SEQ + tq[j]) * 2];
    qx[j] = qv.x * LS;
    qy[j] = qv.y * LS;
  }
  __syncthreads();

  float den[4] = {}, nx[4] = {}, ny[4] = {};

  // bulk: keys [0, qb), no mask needed (s < qb <= tq[j] always)
  const int cb = qb >> 2;
  const int b0 = w * cb, b1 = b0 + cb;
#pragma unroll 2
  for (int s = b0; s < b1; ++s) {
    float4 kvv = skv[s];
#pragma unroll
    for (int j = 0; j < 4; ++j) {
      float sc = fmaf(qx[j], kvv.x, qy[j] * kvv.y);
      float e  = __builtin_amdgcn_exp2f(sc);
      den[j] += e;
      nx[j] = fmaf(e, kvv.z, nx[j]);
      ny[j] = fmaf(e, kvv.w, ny[j]);
    }
  }
  // diagonal: keys [qb + w*64, qb + w*64 + 64), causal mask applies
  const int d0 = qb + w * 64;
#pragma unroll 2
  for (int s = d0; s < d0 + 64; ++s) {
    float4 kvv = skv[s];
#pragma unroll
    for (int j = 0; j < 4; ++j) {
      float sc = fmaf(qx[j], kvv.x, qy[j] * kvv.y);
      float e  = __builtin_amdgcn_exp2f(sc);
      e = (s <= tq[j]) ? e : 0.f;
      den[j] += e;
      nx[j] = fmaf(e, kvv.z, nx[j]);
      ny[j] = fmaf(e, kvv.w, ny[j]);
    }
  }

#pragma unroll
  for (int j = 0; j < 4; ++j) {
    red[w][j * 64 + lane][0] = den[j];
    red[w][j * 64 + lane][1] = nx[j];
    red[w][j * 64 + lane][2] = ny[j];
  }
  __syncthreads();

  // thread tid finalizes query qb+tid
  float dd = 0.f, ax = 0.f, ay = 0.f;
#pragma unroll
  for (int ww = 0; ww < 4; ++ww) {
    dd += red[ww][tid][0];
    ax += red[ww][tid][1];
    ay += red[ww][tid][2];
  }
  float inv = 1.f / dd;
  int b = head >> 7, h = head & 127;
  int t = qb + tid;
  *(float2*)&y[(b * T_SEQ + t) * C_DIM + h * 2] = make_float2(ax * inv, ay * inv);
}

// ---------------------------------------------------------------------------
// Kernel 3: out = y @ w_proj^T (M=2048, N=256, K=256), same MFMA core.
// ---------------------------------------------------------------------------
__global__ __launch_bounds__(256) void k_proj(
    const float* __restrict__ y, const float* __restrict__ wproj,
    float* __restrict__ out)
{
  __shared__ u16 sXhi[64][LDS_K], sXlo[64][LDS_K];
  __shared__ u16 sWhi[64][LDS_K], sWlo[64][LDS_K];

  const int tid  = threadIdx.x;
  const int lane = tid & 63;
  const int w    = tid >> 6;
  const int row0 = blockIdx.x * 64;   // 32
  const int col0 = blockIdx.y * 64;   // 4

  f32x4 acc[4] = {};

  for (int kc = 0; kc < 4; ++kc) {
    stage_hilo(y,     row0, kc * 64, tid, sXhi, sXlo);
    stage_hilo(wproj, col0, kc * 64, tid, sWhi, sWlo);
    __syncthreads();
    mfma_chunk(sXhi, sXlo, sWhi, sWlo, lane, w, acc);
    __syncthreads();
  }

  const int cg = col0 + w * 16 + (lane & 15);
#pragma unroll
  for (int rt = 0; rt < 4; ++rt) {
#pragma unroll
    for (int i = 0; i < 4; ++i) {
      int n = row0 + rt * 16 + (lane >> 4) * 4 + i;
      out[n * C_DIM + cg] = acc[rt][i];
    }
  }
}

// ---------------------------------------------------------------------------
extern "C" void kernel_launch(void* const* d_in, const int* in_sizes, int n_in,
                              void* d_out, int out_size, void* d_ws, size_t ws_size,
                              hipStream_t stream) {
  const float* x     = (const float*)d_in[0];
  const float* wqkv  = (const float*)d_in[1];
  const float* wproj = (const float*)d_in[2];
  const float* qnw   = (const float*)d_in[3];
  const float* knw   = (const float*)d_in[4];

  float* ws = (float*)d_ws;
  float* q  = ws;                       // [BH][T][2]  = 524288 floats (2 MB)
  float* kv = q  + BH * T_SEQ * 2;      // [BH][T][4]  = 1048576 floats (4 MB)
  float* yb = kv + BH * T_SEQ * 4;      // [NTOK][C]   = 524288 floats (2 MB)

  k_qkv <<<dim3(NTOK / 64, 768 / 64),   256, 0, stream>>>(x, wqkv, qnw, knw, q, kv);
  k_attn<<<dim3(BH, 4),                 256, 0, stream>>>(q, kv, yb);
  k_proj<<<dim3(NTOK / 64, C_DIM / 64), 256, 0, stream>>>(yb, wproj, (float*)d_out);
}